// Round 1
// baseline (409.648 us; speedup 1.0000x reference)
//
#include <hip/hip_runtime.h>
#include <hip/hip_bf16.h>
#include <math.h>

typedef unsigned short u16;
typedef short bf16x8 __attribute__((ext_vector_type(8)));
typedef float f32x4 __attribute__((ext_vector_type(4)));

__device__ __forceinline__ u16 f2b(float f){
  union { float f; unsigned u; } c; c.f = f;
  unsigned u = c.u;
  unsigned r = (u + 0x7fffu + ((u >> 16) & 1u)) >> 16;
  return (u16)r;
}
__device__ __forceinline__ float gelu_f(float x){
  return 0.5f * x * (1.0f + erff(x * 0.70710678118654752f));
}

// ---------------------------------------------------------------------------
// Weight prep: convert all weights to bf16, transposed to [N][K] row-major.
// Layout inside wT (u16 elements):
//   WprojT @ 0       (128x128 = 16384)
//   WqT    @ 16384   (2 layers x 512x128 = 131072)
//   WkT    @ 147456  (131072)
//   WvT    @ 278528  (131072)
//   WhT    @ 409600  (2 layers x 128x512 = 131072)
//   WfcT   @ 540672  (2 layers x 128x128 = 65536 -> 32768? no: 2*16384=32768)
//   WcT    @ 573440  (512x128 = 65536)
// total 638976 elements
// ---------------------------------------------------------------------------
__global__ __launch_bounds__(256) void prep_weights(
    const float* __restrict__ Wproj, const float* __restrict__ Wq,
    const float* __restrict__ Wk,    const float* __restrict__ Wv,
    const float* __restrict__ Wh,    const float* __restrict__ Wfc,
    const float* __restrict__ Wc,    u16* __restrict__ wT)
{
  int gid = blockIdx.x * 256 + threadIdx.x;
  if (gid >= 638976) return;
  float val;
  if (gid < 16384) {                       // WprojT[n][k] = Wproj[k][n], 128x128
    int o = gid; int n = o >> 7, k = o & 127;
    val = Wproj[k * 128 + n];
  } else if (gid < 147456) {               // WqT[l][n][k] = Wq[l][k][n], [128][512]
    int o = gid - 16384; int l = o >> 16, oo = o & 65535;
    int n = oo >> 7, k = oo & 127;
    val = Wq[l * 65536 + k * 512 + n];
  } else if (gid < 278528) {
    int o = gid - 147456; int l = o >> 16, oo = o & 65535;
    int n = oo >> 7, k = oo & 127;
    val = Wk[l * 65536 + k * 512 + n];
  } else if (gid < 409600) {
    int o = gid - 278528; int l = o >> 16, oo = o & 65535;
    int n = oo >> 7, k = oo & 127;
    val = Wv[l * 65536 + k * 512 + n];
  } else if (gid < 540672) {               // WhT[l][n][k] = Wh[l][k][n], in [512][128]
    int o = gid - 409600; int l = o >> 16, oo = o & 65535;
    int n = oo >> 9, k = oo & 511;
    val = Wh[l * 65536 + k * 128 + n];
  } else if (gid < 573440) {               // WfcT[l][n][k], in [128][128]
    int o = gid - 540672; int l = o >> 14, oo = o & 16383;
    int n = oo >> 7, k = oo & 127;
    val = Wfc[l * 16384 + k * 128 + n];
  } else {                                 // WcT[n][k] = Wc[k][n], in [128][512]
    int o = gid - 573440; int n = o >> 7, k = o & 127;
    val = Wc[k * 512 + n];
  }
  wT[gid] = f2b(val);
}

// ---------------------------------------------------------------------------
// x -> bf16 copy + per-row validity (any feature nonzero)
// ---------------------------------------------------------------------------
__global__ __launch_bounds__(128) void prep_x(
    const float* __restrict__ x, u16* __restrict__ xb, float* __restrict__ valid)
{
  __shared__ int flag;
  int r = blockIdx.x, c = threadIdx.x;
  if (c == 0) flag = 0;
  __syncthreads();
  float v = x[r * 128 + c];
  xb[r * 128 + c] = f2b(v);
  if (v != 0.0f) atomicOr(&flag, 1);
  __syncthreads();
  if (c == 0) valid[r] = flag ? 1.0f : 0.0f;
}

// ---------------------------------------------------------------------------
// Generic GEMM: C[M x N] = A[M x K] @ Bt[N x K]^T, bf16 inputs, f32 acc.
// 64x64 block tile, 256 threads, 4 waves each 32x32 (2x2 of 16x16x32 MFMA).
// modes:
//  1 GELU_MASK : g = gelu(acc)*valid[r]; outf[r][c]=g; outb[r][c]=bf16(g)
//  2 QK_SPLIT  : outb[((s*4+h)*128+m)*128+d] = bf16(acc)   (r=s*128+m, c=h*128+d)
//  3 V_SPLIT   : outb[((s*4+h)*128+d)*128+m] = bf16(acc)
//  4 ADD_MASK  : outf[r][c] = hin[r][c] + acc*valid[r]          (N==128)
//  5 GELU_ADD  : outf[r][c] = hin[r][c] + gelu(acc)*valid[r]    (N==128)
// ---------------------------------------------------------------------------
__global__ __launch_bounds__(256) void gemm_bt(
    const u16* __restrict__ A, const u16* __restrict__ Bt,
    float* __restrict__ outf, u16* __restrict__ outb,
    const float* __restrict__ hin, const float* __restrict__ valid,
    int N, int K, int mode)
{
  __shared__ __align__(16) u16 As[64 * 136];
  __shared__ __align__(16) u16 Bs[64 * 136];
  int tid = threadIdx.x;
  int wave = tid >> 6, lane = tid & 63, quad = lane >> 4, l16 = lane & 15;
  int bm = blockIdx.x, bn = blockIdx.y;
  int wm = (wave >> 1) * 32, wn = (wave & 1) * 32;
  f32x4 acc[2][2] = {};
  int nk = K >> 7;
  for (int kk = 0; kk < nk; ++kk) {
    for (int i = 0; i < 4; ++i) {
      int ch = tid + i * 256;           // 0..1023
      int r = ch >> 4, cc = ch & 15;
      *(uint4*)(As + r * 136 + cc * 8) =
          *(const uint4*)(A + (size_t)(bm * 64 + r) * K + kk * 128 + cc * 8);
      *(uint4*)(Bs + r * 136 + cc * 8) =
          *(const uint4*)(Bt + (size_t)(bn * 64 + r) * K + kk * 128 + cc * 8);
    }
    __syncthreads();
    for (int ks = 0; ks < 4; ++ks) {
      bf16x8 aF[2], bF[2];
      for (int i = 0; i < 2; ++i)
        aF[i] = *(const bf16x8*)(As + (wm + i * 16 + l16) * 136 + ks * 32 + quad * 8);
      for (int j = 0; j < 2; ++j)
        bF[j] = *(const bf16x8*)(Bs + (wn + j * 16 + l16) * 136 + ks * 32 + quad * 8);
      for (int i = 0; i < 2; ++i)
        for (int j = 0; j < 2; ++j)
          acc[i][j] = __builtin_amdgcn_mfma_f32_16x16x32_bf16(aF[i], bF[j], acc[i][j], 0, 0, 0);
    }
    __syncthreads();
  }
  for (int i = 0; i < 2; ++i)
    for (int j = 0; j < 2; ++j)
      for (int g = 0; g < 4; ++g) {
        int r = bm * 64 + wm + i * 16 + quad * 4 + g;
        int c = bn * 64 + wn + j * 16 + l16;
        float a = acc[i][j][g];
        if (mode == 1) {
          float gg = gelu_f(a) * valid[r];
          outf[(size_t)r * N + c] = gg;
          outb[(size_t)r * N + c] = f2b(gg);
        } else if (mode == 2) {
          int s = r >> 7, m = r & 127, hh = c >> 7, d = c & 127;
          outb[(size_t)(((s * 4 + hh) * 128 + m)) * 128 + d] = f2b(a);
        } else if (mode == 3) {
          int s = r >> 7, m = r & 127, hh = c >> 7, d = c & 127;
          outb[(size_t)(((s * 4 + hh) * 128 + d)) * 128 + m] = f2b(a);
        } else if (mode == 4) {
          outf[(size_t)r * N + c] = hin[(size_t)r * N + c] + a * valid[r];
        } else if (mode == 5) {
          outf[(size_t)r * N + c] = hin[(size_t)r * N + c] + gelu_f(a) * valid[r];
        } else {
          outf[(size_t)r * N + c] = a;
        }
      }
}

// ---------------------------------------------------------------------------
// set_norm: per set s, u[16384] -> hf, hb. mean = S1/(size*128),
// var = S2/(size*128) - mean^2 (pad rows are exact zeros).
// ---------------------------------------------------------------------------
__global__ __launch_bounds__(256) void setnorm(
    const float* __restrict__ u, float* __restrict__ hf, u16* __restrict__ hb,
    const float* __restrict__ valid, const int* __restrict__ xsize)
{
  __shared__ float r1[4], r2[4];
  int s = blockIdx.x, tid = threadIdx.x, wave = tid >> 6, lane = tid & 63;
  size_t base = (size_t)s * 16384;
  float s1 = 0.f, s2 = 0.f;
  for (int idx = tid; idx < 16384; idx += 256) {
    float v = u[base + idx];
    s1 += v; s2 += v * v;
  }
  for (int off = 1; off < 64; off <<= 1) {
    s1 += __shfl_xor(s1, off, 64);
    s2 += __shfl_xor(s2, off, 64);
  }
  if (lane == 0) { r1[wave] = s1; r2[wave] = s2; }
  __syncthreads();
  float S1 = r1[0] + r1[1] + r1[2] + r1[3];
  float S2 = r2[0] + r2[1] + r2[2] + r2[3];
  int sz = xsize[s]; if (sz < 1) sz = 1;
  float denom = (float)sz * 128.0f;
  float mean = S1 / denom;
  float var = S2 / denom - mean * mean;
  if (var < 0.f) var = 0.f;
  float inv = 1.0f / (sqrtf(var) + 1e-8f);
  for (int idx = tid; idx < 16384; idx += 256) {
    int r = idx >> 7;
    float vl = valid[s * 128 + r];
    float v = (u[base + idx] - mean) * inv * vl;
    hf[base + idx] = v;
    hb[base + idx] = f2b(v);
  }
}

// ---------------------------------------------------------------------------
// Attention per (set, head): s = q k^T / sqrt(128); value-masked softmax
// (mask = s != 0, max over raw row incl. exact zeros, matches reference);
// o = a @ v. q,k: [s][h][m][d]; vT: [s][h][d][n]; o -> [6144][512] bf16.
// ---------------------------------------------------------------------------
__global__ __launch_bounds__(256) void attn_kernel(
    const u16* __restrict__ qg, const u16* __restrict__ kg,
    const u16* __restrict__ vTg, u16* __restrict__ og)
{
  __shared__ __align__(16) u16 bufA[128 * 136];
  __shared__ __align__(16) u16 bufB[128 * 136];
  int tid = threadIdx.x, wave = tid >> 6, lane = tid & 63, quad = lane >> 4, l16 = lane & 15;
  int bid = blockIdx.x;
  int s = bid >> 2, hh = bid & 3;
  size_t base = (size_t)bid * 16384;
  for (int t = 0; t < 8; ++t) {
    int ch = tid + t * 256; int r = ch >> 4, cc = ch & 15;
    *(uint4*)(bufA + r * 136 + cc * 8) = *(const uint4*)(qg + base + r * 128 + cc * 8);
    *(uint4*)(bufB + r * 136 + cc * 8) = *(const uint4*)(kg + base + r * 128 + cc * 8);
  }
  __syncthreads();
  int wm = wave * 32;
  f32x4 acc[2][8] = {};
  for (int ks = 0; ks < 4; ++ks) {
    bf16x8 aF[2], bF[8];
    for (int i = 0; i < 2; ++i)
      aF[i] = *(const bf16x8*)(bufA + (wm + i * 16 + l16) * 136 + ks * 32 + quad * 8);
    for (int j = 0; j < 8; ++j)
      bF[j] = *(const bf16x8*)(bufB + (j * 16 + l16) * 136 + ks * 32 + quad * 8);
    for (int i = 0; i < 2; ++i)
      for (int j = 0; j < 8; ++j)
        acc[i][j] = __builtin_amdgcn_mfma_f32_16x16x32_bf16(aF[i], bF[j], acc[i][j], 0, 0, 0);
  }
  const float rs = 0.08838834764831845f;  // 1/sqrt(128)
  // softmax per row; each wave owns rows [wm, wm+32) -> writes a into bufA rows
  for (int i = 0; i < 2; ++i)
    for (int g = 0; g < 4; ++g) {
      int rl = wm + i * 16 + quad * 4 + g;
      float vals[8]; float rmax = -1e30f;
      for (int j = 0; j < 8; ++j) {
        float v = acc[i][j][g] * rs;
        vals[j] = v;
        rmax = fmaxf(rmax, v);
      }
      for (int off = 1; off < 16; off <<= 1) rmax = fmaxf(rmax, __shfl_xor(rmax, off, 64));
      float rsum = 0.f;
      for (int j = 0; j < 8; ++j) {
        float e = (vals[j] != 0.0f) ? expf(vals[j] - rmax) : 0.0f;
        vals[j] = e; rsum += e;
      }
      for (int off = 1; off < 16; off <<= 1) rsum += __shfl_xor(rsum, off, 64);
      float inv = 1.0f / (rsum + 1e-10f);
      for (int j = 0; j < 8; ++j)
        bufA[rl * 136 + j * 16 + l16] = f2b(vals[j] * inv);
    }
  __syncthreads();  // everyone done reading bufB (k)
  for (int t = 0; t < 8; ++t) {
    int ch = tid + t * 256; int r = ch >> 4, cc = ch & 15;
    *(uint4*)(bufB + r * 136 + cc * 8) = *(const uint4*)(vTg + base + r * 128 + cc * 8);
  }
  __syncthreads();
  f32x4 acc2[2][8] = {};
  for (int ks = 0; ks < 4; ++ks) {
    bf16x8 aF[2], bF[8];
    for (int i = 0; i < 2; ++i)
      aF[i] = *(const bf16x8*)(bufA + (wm + i * 16 + l16) * 136 + ks * 32 + quad * 8);
    for (int j = 0; j < 8; ++j)
      bF[j] = *(const bf16x8*)(bufB + (j * 16 + l16) * 136 + ks * 32 + quad * 8);
    for (int i = 0; i < 2; ++i)
      for (int j = 0; j < 8; ++j)
        acc2[i][j] = __builtin_amdgcn_mfma_f32_16x16x32_bf16(aF[i], bF[j], acc2[i][j], 0, 0, 0);
  }
  for (int i = 0; i < 2; ++i)
    for (int j = 0; j < 8; ++j)
      for (int g = 0; g < 4; ++g) {
        int rl = wm + i * 16 + quad * 4 + g;
        int d = j * 16 + l16;
        og[(size_t)(s * 128 + rl) * 512 + hh * 128 + d] = f2b(acc2[i][j][g]);
      }
}

// ---------------------------------------------------------------------------
// Cross-set: per (j,i,h) block: sum_{m,n} leaky(z_j[m]·z_i[n] / sqrt(128)),
// scores[j][i][h] = sum / (size_i * 128). z in q-layout [s][h][m][d].
// ---------------------------------------------------------------------------
__global__ __launch_bounds__(256) void cross_kernel(
    const u16* __restrict__ zg, float* __restrict__ scores, const int* __restrict__ xsize)
{
  __shared__ __align__(16) u16 bufA[128 * 136];
  __shared__ __align__(16) u16 bufB[128 * 136];
  __shared__ float red[4];
  int tid = threadIdx.x, wave = tid >> 6, lane = tid & 63, quad = lane >> 4, l16 = lane & 15;
  int j = blockIdx.x, i = blockIdx.y, hh = blockIdx.z;
  size_t basej = ((size_t)j * 4 + hh) * 16384;
  size_t basei = ((size_t)i * 4 + hh) * 16384;
  for (int t = 0; t < 8; ++t) {
    int ch = tid + t * 256; int r = ch >> 4, cc = ch & 15;
    *(uint4*)(bufA + r * 136 + cc * 8) = *(const uint4*)(zg + basej + r * 128 + cc * 8);
    *(uint4*)(bufB + r * 136 + cc * 8) = *(const uint4*)(zg + basei + r * 128 + cc * 8);
  }
  __syncthreads();
  int wm = wave * 32;
  f32x4 acc[2][8] = {};
  for (int ks = 0; ks < 4; ++ks) {
    bf16x8 aF[2], bF[8];
    for (int ii = 0; ii < 2; ++ii)
      aF[ii] = *(const bf16x8*)(bufA + (wm + ii * 16 + l16) * 136 + ks * 32 + quad * 8);
    for (int jj = 0; jj < 8; ++jj)
      bF[jj] = *(const bf16x8*)(bufB + (jj * 16 + l16) * 136 + ks * 32 + quad * 8);
    for (int ii = 0; ii < 2; ++ii)
      for (int jj = 0; jj < 8; ++jj)
        acc[ii][jj] = __builtin_amdgcn_mfma_f32_16x16x32_bf16(aF[ii], bF[jj], acc[ii][jj], 0, 0, 0);
  }
  const float rs = 0.08838834764831845f;
  float lsum = 0.f;
  for (int ii = 0; ii < 2; ++ii)
    for (int jj = 0; jj < 8; ++jj)
      for (int g = 0; g < 4; ++g) {
        float v = acc[ii][jj][g] * rs;
        lsum += (v >= 0.f) ? v : 0.3f * v;
      }
  for (int off = 1; off < 64; off <<= 1) lsum += __shfl_xor(lsum, off, 64);
  if (lane == 0) red[wave] = lsum;
  __syncthreads();
  if (tid == 0) {
    float tot = red[0] + red[1] + red[2] + red[3];
    int sz = xsize[i]; if (sz < 1) sz = 1;
    scores[((j * 48 + i) << 2) + hh] = tot / ((float)sz * 128.0f);
  }
}

__global__ __launch_bounds__(256) void final_kernel(
    const float* __restrict__ scores, const float* __restrict__ w2, float* __restrict__ out)
{
  int idx = blockIdx.x * 256 + threadIdx.x;
  if (idx >= 2304) return;
  float t = 0.f;
  for (int h = 0; h < 4; ++h) t += scores[idx * 4 + h] * w2[h];
  out[idx] = t;
}

// ---------------------------------------------------------------------------
extern "C" void kernel_launch(void* const* d_in, const int* in_sizes, int n_in,
                              void* d_out, int out_size, void* d_ws, size_t ws_size,
                              hipStream_t stream)
{
  const float* x     = (const float*)d_in[0];
  const int*   xsize = (const int*)d_in[1];
  const float* Wproj = (const float*)d_in[2];
  const float* Wq    = (const float*)d_in[3];
  const float* Wk    = (const float*)d_in[4];
  const float* Wv    = (const float*)d_in[5];
  const float* Wh    = (const float*)d_in[6];
  const float* Wfc   = (const float*)d_in[7];
  const float* Wc    = (const float*)d_in[8];
  const float* w2    = (const float*)d_in[9];
  float* out = (float*)d_out;

  char* ws = (char*)d_ws;
  size_t off = 0;
  auto alloc = [&](size_t bytes) -> char* {
    char* p = ws + off;
    off += (bytes + 255) & ~(size_t)255;
    return p;
  };
  u16*   wT    = (u16*)  alloc(638976 * 2);
  u16*   xb    = (u16*)  alloc(6144 * 128 * 2);
  float* valid = (float*)alloc(6144 * 4);
  float* hf    = (float*)alloc(6144 * 128 * 4);
  u16*   hb    = (u16*)  alloc(6144 * 128 * 2);
  float* uf    = (float*)alloc(6144 * 128 * 4);
  u16*   qb    = (u16*)  alloc((size_t)3145728 * 2);
  u16*   kb    = (u16*)  alloc((size_t)3145728 * 2);
  u16*   vTb   = (u16*)  alloc((size_t)3145728 * 2);
  u16*   ob    = (u16*)  alloc((size_t)6144 * 512 * 2);
  float* sc    = (float*)alloc(9216 * 4);

  prep_weights<<<2496, 256, 0, stream>>>(Wproj, Wq, Wk, Wv, Wh, Wfc, Wc, wT);
  prep_x<<<6144, 128, 0, stream>>>(x, xb, valid);
  // h = gelu(x @ Wproj) * mask
  gemm_bt<<<dim3(96, 2), 256, 0, stream>>>(xb, wT, hf, hb, nullptr, valid, 128, 128, 1);

  for (int l = 0; l < 2; ++l) {
    const u16* WqT  = wT + 16384  + l * 65536;
    const u16* WkT  = wT + 147456 + l * 65536;
    const u16* WvT  = wT + 278528 + l * 65536;
    const u16* WhT  = wT + 409600 + l * 65536;
    const u16* WfcT = wT + 540672 + l * 16384;
    gemm_bt<<<dim3(96, 8), 256, 0, stream>>>(hb, WqT, nullptr, qb,  nullptr, nullptr, 512, 128, 2);
    gemm_bt<<<dim3(96, 8), 256, 0, stream>>>(hb, WkT, nullptr, kb,  nullptr, nullptr, 512, 128, 2);
    gemm_bt<<<dim3(96, 8), 256, 0, stream>>>(hb, WvT, nullptr, vTb, nullptr, nullptr, 512, 128, 3);
    attn_kernel<<<192, 256, 0, stream>>>(qb, kb, vTb, ob);
    gemm_bt<<<dim3(96, 2), 256, 0, stream>>>(ob, WhT, uf, nullptr, hf, valid, 128, 512, 4);
    setnorm<<<48, 256, 0, stream>>>(uf, hf, hb, valid, xsize);
    gemm_bt<<<dim3(96, 2), 256, 0, stream>>>(hb, WfcT, uf, nullptr, hf, valid, 128, 128, 5);
    setnorm<<<48, 256, 0, stream>>>(uf, hf, hb, valid, xsize);
  }

  // z = h @ Wc, stored per-head in q-layout (reuse qb)
  const u16* WcT = wT + 573440;
  gemm_bt<<<dim3(96, 8), 256, 0, stream>>>(hb, WcT, nullptr, qb, nullptr, nullptr, 512, 128, 2);
  cross_kernel<<<dim3(48, 48, 4), 256, 0, stream>>>(qb, sc, xsize);
  final_kernel<<<9, 256, 0, stream>>>(sc, w2, out);
}

// Round 2
// 293.699 us; speedup vs baseline: 1.3948x; 1.3948x over previous
//
#include <hip/hip_runtime.h>
#include <hip/hip_bf16.h>
#include <math.h>

typedef unsigned short u16;
typedef short bf16x8 __attribute__((ext_vector_type(8)));
typedef float f32x4 __attribute__((ext_vector_type(4)));
typedef float f32x16 __attribute__((ext_vector_type(16)));

__device__ __forceinline__ u16 f2b(float f){
  union { float f; unsigned u; } c; c.f = f;
  unsigned u = c.u;
  unsigned r = (u + 0x7fffu + ((u >> 16) & 1u)) >> 16;
  return (u16)r;
}
__device__ __forceinline__ float gelu_f(float x){
  return 0.5f * x * (1.0f + erff(x * 0.70710678118654752f));
}

// ---------------------------------------------------------------------------
// Weight prep -> bf16 [N][K] row-major. Layout in wT (u16 elements):
//   WprojT  @ 0       (128x128)
//   QKVT    @ 16384   (2 layers x [1536][128]; rows 0-511 Wq^T, 512-1023 Wk^T,
//                      1024-1535 Wv^T)
//   WhT     @ 409600  (2 x [128][512])
//   WfcT    @ 540672  (2 x [128][128])
//   WcT     @ 573440  ([512][128])
// gid in [638976, 639360): zero the 384-float stats buffer.
// ---------------------------------------------------------------------------
__global__ __launch_bounds__(256) void prep_weights(
    const float* __restrict__ Wproj, const float* __restrict__ Wq,
    const float* __restrict__ Wk,    const float* __restrict__ Wv,
    const float* __restrict__ Wh,    const float* __restrict__ Wfc,
    const float* __restrict__ Wc,    u16* __restrict__ wT,
    float* __restrict__ stats)
{
  int gid = blockIdx.x * 256 + threadIdx.x;
  if (gid >= 639360) return;
  if (gid >= 638976) { stats[gid - 638976] = 0.0f; return; }
  float val;
  if (gid < 16384) {
    int n = gid >> 7, k = gid & 127;
    val = Wproj[k * 128 + n];
  } else if (gid < 409600) {               // fused QKV^T
    int o = gid - 16384; int l = o / 196608, oo = o - l * 196608;
    int n = oo >> 7, k = oo & 127;
    if (n < 512)       val = Wq[l * 65536 + k * 512 + n];
    else if (n < 1024) val = Wk[l * 65536 + k * 512 + (n - 512)];
    else               val = Wv[l * 65536 + k * 512 + (n - 1024)];
  } else if (gid < 540672) {               // WhT[l][n][k], in [512][128]
    int o = gid - 409600; int l = o >> 16, oo = o & 65535;
    int n = oo >> 9, k = oo & 511;
    val = Wh[l * 65536 + k * 128 + n];
  } else if (gid < 573440) {               // WfcT
    int o = gid - 540672; int l = o >> 14, oo = o & 16383;
    int n = oo >> 7, k = oo & 127;
    val = Wfc[l * 16384 + k * 128 + n];
  } else {                                 // WcT[n][k], in [128][512]
    int o = gid - 573440; int n = o >> 7, k = o & 127;
    val = Wc[k * 512 + n];
  }
  wT[gid] = f2b(val);
}

__global__ __launch_bounds__(128) void prep_x(
    const float* __restrict__ x, u16* __restrict__ xb, float* __restrict__ valid)
{
  __shared__ int flag;
  int r = blockIdx.x, c = threadIdx.x;
  if (c == 0) flag = 0;
  __syncthreads();
  float v = x[r * 128 + c];
  xb[r * 128 + c] = f2b(v);
  if (v != 0.0f) atomicOr(&flag, 1);
  __syncthreads();
  if (c == 0) valid[r] = flag ? 1.0f : 0.0f;
}

// ---------------------------------------------------------------------------
// Generic GEMM: C[M x N] = A[M x K] @ Bt[N x K]^T. 64x64 tile, 256 thr.
// modes:
//  1 GELU_MASK : g=gelu(acc)*valid[r] -> outf, outb            (N=128)
//  4 ADD_MASK  : u=hin+acc*valid[r]   -> outf, stats atomics   (N=128)
//  5 GELU_ADD  : u=hin+gelu(acc)*valid[r] -> outf, stats       (N=128)
//  6 QKV       : c<512 -> q[s][h][m][d]; <1024 -> k; else vT[s][h][d][m]
// ---------------------------------------------------------------------------
__global__ __launch_bounds__(256) void gemm_bt(
    const u16* __restrict__ A, const u16* __restrict__ Bt,
    float* __restrict__ outf, u16* __restrict__ outb,
    u16* __restrict__ outb2, u16* __restrict__ outb3,
    const float* __restrict__ hin, const float* __restrict__ valid,
    float* __restrict__ stats, int N, int K, int mode)
{
  __shared__ __align__(16) u16 As[64 * 136];
  __shared__ __align__(16) u16 Bs[64 * 136];
  __shared__ float red[8];
  int tid = threadIdx.x;
  int wave = tid >> 6, lane = tid & 63, quad = lane >> 4, l16 = lane & 15;
  int bm = blockIdx.x, bn = blockIdx.y;
  int wm = (wave >> 1) * 32, wn = (wave & 1) * 32;
  f32x4 acc[2][2] = {};
  int nk = K >> 7;
  for (int kk = 0; kk < nk; ++kk) {
    for (int i = 0; i < 4; ++i) {
      int ch = tid + i * 256;
      int r = ch >> 4, cc = ch & 15;
      *(uint4*)(As + r * 136 + cc * 8) =
          *(const uint4*)(A + (size_t)(bm * 64 + r) * K + kk * 128 + cc * 8);
      *(uint4*)(Bs + r * 136 + cc * 8) =
          *(const uint4*)(Bt + (size_t)(bn * 64 + r) * K + kk * 128 + cc * 8);
    }
    __syncthreads();
    for (int ks = 0; ks < 4; ++ks) {
      bf16x8 aF[2], bF[2];
      for (int i = 0; i < 2; ++i)
        aF[i] = *(const bf16x8*)(As + (wm + i * 16 + l16) * 136 + ks * 32 + quad * 8);
      for (int j = 0; j < 2; ++j)
        bF[j] = *(const bf16x8*)(Bs + (wn + j * 16 + l16) * 136 + ks * 32 + quad * 8);
      for (int i = 0; i < 2; ++i)
        for (int j = 0; j < 2; ++j)
          acc[i][j] = __builtin_amdgcn_mfma_f32_16x16x32_bf16(aF[i], bF[j], acc[i][j], 0, 0, 0);
    }
    __syncthreads();
  }
  float ls1 = 0.f, ls2 = 0.f;
  for (int i = 0; i < 2; ++i)
    for (int j = 0; j < 2; ++j)
      for (int g = 0; g < 4; ++g) {
        int r = bm * 64 + wm + i * 16 + quad * 4 + g;
        int c = bn * 64 + wn + j * 16 + l16;
        float a = acc[i][j][g];
        if (mode == 1) {
          float gg = gelu_f(a) * valid[r];
          outf[(size_t)r * N + c] = gg;
          outb[(size_t)r * N + c] = f2b(gg);
        } else if (mode == 4 || mode == 5) {
          float add = (mode == 5) ? gelu_f(a) : a;
          float u = hin[(size_t)r * N + c] + add * valid[r];
          outf[(size_t)r * N + c] = u;
          ls1 += u; ls2 += u * u;
        } else { // mode 6
          int s = r >> 7, m = r & 127;
          if (c < 512) {
            int hh = c >> 7, d = c & 127;
            outb[(size_t)(((s * 4 + hh) * 128 + m)) * 128 + d] = f2b(a);
          } else if (c < 1024) {
            int c2 = c - 512, hh = c2 >> 7, d = c2 & 127;
            outb2[(size_t)(((s * 4 + hh) * 128 + m)) * 128 + d] = f2b(a);
          } else {
            int c2 = c - 1024, hh = c2 >> 7, d = c2 & 127;
            outb3[(size_t)(((s * 4 + hh) * 128 + d)) * 128 + m] = f2b(a);
          }
        }
      }
  if (mode == 4 || mode == 5) {
    for (int off = 1; off < 64; off <<= 1) {
      ls1 += __shfl_xor(ls1, off, 64);
      ls2 += __shfl_xor(ls2, off, 64);
    }
    if (lane == 0) { red[wave * 2] = ls1; red[wave * 2 + 1] = ls2; }
    __syncthreads();
    if (tid == 0) {
      float S1 = red[0] + red[2] + red[4] + red[6];
      float S2 = red[1] + red[3] + red[5] + red[7];
      int s = bm >> 1;
      atomicAdd(stats + s * 2, S1);
      atomicAdd(stats + s * 2 + 1, S2);
    }
  }
}

// ---------------------------------------------------------------------------
// normalize: u -> (u-mean)*inv*valid, using pre-accumulated stats[s]={S1,S2}.
// 192 blocks x 256 threads, 16 contiguous elems per thread.
// ---------------------------------------------------------------------------
__global__ __launch_bounds__(256) void normalize(
    const float* __restrict__ uf, float* __restrict__ hf, u16* __restrict__ hb,
    const float* __restrict__ valid, const float* __restrict__ stats,
    const int* __restrict__ xsize)
{
  int g = blockIdx.x * 256 + threadIdx.x;   // [0, 49152)
  int s = g >> 10;
  int row = g >> 3;
  float S1 = stats[s * 2], S2 = stats[s * 2 + 1];
  int sz = xsize[s]; if (sz < 1) sz = 1;
  float denom = (float)sz * 128.0f;
  float mean = S1 / denom;
  float var = S2 / denom - mean * mean; if (var < 0.f) var = 0.f;
  float inv = 1.0f / (sqrtf(var) + 1e-8f);
  float vl = valid[row];
  size_t base = (size_t)g * 16;
  for (int t = 0; t < 4; ++t) {
    float4 u = *(const float4*)(uf + base + t * 4);
    float4 v;
    v.x = (u.x - mean) * inv * vl;
    v.y = (u.y - mean) * inv * vl;
    v.z = (u.z - mean) * inv * vl;
    v.w = (u.w - mean) * inv * vl;
    *(float4*)(hf + base + t * 4) = v;
    uint2 p;
    p.x = (unsigned)f2b(v.x) | ((unsigned)f2b(v.y) << 16);
    p.y = (unsigned)f2b(v.z) | ((unsigned)f2b(v.w) << 16);
    *(uint2*)(hb + base + t * 4) = p;
  }
}

// ---------------------------------------------------------------------------
// Attention per (set, head), size-trimmed. q,k:[s][h][m][d]; vT:[s][h][d][n].
// Tiles beyond ceil(sz/16) are zero (pad rows exact zeros) -> skipped; PV
// K-tiles >= ceil(sz/32) contribute 0 because v pad rows are zero.
// ---------------------------------------------------------------------------
__global__ __launch_bounds__(256) void attn_kernel(
    const u16* __restrict__ qg, const u16* __restrict__ kg,
    const u16* __restrict__ vTg, u16* __restrict__ og,
    const int* __restrict__ xsize)
{
  __shared__ __align__(16) u16 bufA[128 * 136];
  __shared__ __align__(16) u16 bufB[128 * 136];
  int tid = threadIdx.x, wave = tid >> 6, lane = tid & 63, quad = lane >> 4, l16 = lane & 15;
  int bid = blockIdx.x;
  int s = bid >> 2, hh = bid & 3;
  int sz = xsize[s]; if (sz < 1) sz = 1;
  int Mt = (sz + 15) >> 4;     // active 16-tiles in m/n
  int Mk = (sz + 31) >> 5;     // active 32-wide K tiles for PV
  size_t base = (size_t)bid * 16384;
  for (int t = 0; t < 8; ++t) {
    if (t < Mt) {
      int ch = tid + t * 256; int r = ch >> 4, cc = ch & 15;
      *(uint4*)(bufA + r * 136 + cc * 8) = *(const uint4*)(qg + base + r * 128 + cc * 8);
      *(uint4*)(bufB + r * 136 + cc * 8) = *(const uint4*)(kg + base + r * 128 + cc * 8);
    }
  }
  __syncthreads();
  int wm = wave * 32;
  bool act0 = (wave * 2) < Mt, act1 = (wave * 2 + 1) < Mt;
  f32x4 acc[2][8] = {};
  if (act0 || act1) {
    for (int ks = 0; ks < 4; ++ks) {
      bf16x8 aF[2], bF[8];
      if (act0) aF[0] = *(const bf16x8*)(bufA + (wm + l16) * 136 + ks * 32 + quad * 8);
      if (act1) aF[1] = *(const bf16x8*)(bufA + (wm + 16 + l16) * 136 + ks * 32 + quad * 8);
#pragma unroll
      for (int j = 0; j < 8; ++j)
        if (j < Mt) bF[j] = *(const bf16x8*)(bufB + (j * 16 + l16) * 136 + ks * 32 + quad * 8);
#pragma unroll
      for (int j = 0; j < 8; ++j)
        if (j < Mt) {
          if (act0) acc[0][j] = __builtin_amdgcn_mfma_f32_16x16x32_bf16(aF[0], bF[j], acc[0][j], 0, 0, 0);
          if (act1) acc[1][j] = __builtin_amdgcn_mfma_f32_16x16x32_bf16(aF[1], bF[j], acc[1][j], 0, 0, 0);
        }
    }
  }
  const float rs = 0.08838834764831845f;
  for (int i = 0; i < 2; ++i) {
    bool act = i ? act1 : act0;
    if (!act) continue;
    for (int g = 0; g < 4; ++g) {
      int rl = wm + i * 16 + quad * 4 + g;
      float vals[8]; float rmax = -1e30f;
#pragma unroll
      for (int j = 0; j < 8; ++j)
        if (j < Mt) {
          float v = acc[i][j][g] * rs;
          vals[j] = v;
          rmax = fmaxf(rmax, v);
        }
      for (int off = 1; off < 16; off <<= 1) rmax = fmaxf(rmax, __shfl_xor(rmax, off, 64));
      if (sz < 128) rmax = fmaxf(rmax, 0.0f);   // reference max includes pad zeros
      float rsum = 0.f;
#pragma unroll
      for (int j = 0; j < 8; ++j)
        if (j < Mt) {
          float e = (vals[j] != 0.0f) ? expf(vals[j] - rmax) : 0.0f;
          vals[j] = e; rsum += e;
        }
      for (int off = 1; off < 16; off <<= 1) rsum += __shfl_xor(rsum, off, 64);
      float inv = 1.0f / (rsum + 1e-10f);
#pragma unroll
      for (int j = 0; j < 8; ++j)
        if (j < Mt) bufA[rl * 136 + j * 16 + l16] = f2b(vals[j] * inv);
    }
  }
  __syncthreads();
  for (int t = 0; t < 8; ++t) {
    int ch = tid + t * 256; int r = ch >> 4, cc = ch & 15;
    *(uint4*)(bufB + r * 136 + cc * 8) = *(const uint4*)(vTg + base + r * 128 + cc * 8);
  }
  __syncthreads();
  f32x4 acc2[2][8] = {};
  if (act0 || act1) {
    for (int ks = 0; ks < Mk; ++ks) {
      bf16x8 aF[2], bF[8];
      if (act0) aF[0] = *(const bf16x8*)(bufA + (wm + l16) * 136 + ks * 32 + quad * 8);
      if (act1) aF[1] = *(const bf16x8*)(bufA + (wm + 16 + l16) * 136 + ks * 32 + quad * 8);
#pragma unroll
      for (int j = 0; j < 8; ++j)
        bF[j] = *(const bf16x8*)(bufB + (j * 16 + l16) * 136 + ks * 32 + quad * 8);
#pragma unroll
      for (int j = 0; j < 8; ++j) {
        if (act0) acc2[0][j] = __builtin_amdgcn_mfma_f32_16x16x32_bf16(aF[0], bF[j], acc2[0][j], 0, 0, 0);
        if (act1) acc2[1][j] = __builtin_amdgcn_mfma_f32_16x16x32_bf16(aF[1], bF[j], acc2[1][j], 0, 0, 0);
      }
    }
  }
  for (int i = 0; i < 2; ++i)
    for (int j = 0; j < 8; ++j)
      for (int g = 0; g < 4; ++g) {
        int rl = wm + i * 16 + quad * 4 + g;
        int d = j * 16 + l16;
        og[(size_t)(s * 128 + rl) * 512 + hh * 128 + d] = f2b(acc2[i][j][g]);
      }
}

// ---------------------------------------------------------------------------
// Cross-set, symmetric + size-trimmed, 32x32x16 MFMA, fragment-order LDS.
// Raw sum T[j,i,h] = T[i,j,h]; scores[j][i][h] = T/(size_i*128).
// leaky(x) = 0.65x + 0.35|x|.
// Fragment-order LDS: chunk index c=(g<<9)|(ks<<6)|(half<<5)|m holds
// z[g*32+m][ks*16+half*8 .. +8]; lane l of (g,ks) reads chunk (g*8+ks)*64+l
// -> lane-linear, conflict-free.
// ---------------------------------------------------------------------------
__global__ __launch_bounds__(256) void cross_kernel(
    const u16* __restrict__ zg, float* __restrict__ scores, const int* __restrict__ xsize)
{
  int j = blockIdx.x, i = blockIdx.y;
  if (j > i) return;
  int hh = blockIdx.z;
  __shared__ __align__(16) u16 bufA[16384];
  __shared__ __align__(16) u16 bufB[16384];
  __shared__ float red[8];
  int tid = threadIdx.x, wave = tid >> 6, lane = tid & 63;
  int sj = xsize[j]; if (sj < 1) sj = 1;
  int si = xsize[i]; if (si < 1) si = 1;
  int MjT = (sj + 31) >> 5, MiT = (si + 31) >> 5;   // 1..4 active 32-tiles
  size_t basej = ((size_t)j * 4 + hh) * 16384;
  size_t basei = ((size_t)i * 4 + hh) * 16384;
  for (int t = 0; t < 8; ++t) {
    int c = t * 256 + tid;
    int m = c & 31, half = (c >> 5) & 1, ks = (c >> 6) & 7, g = c >> 9;
    int row = g * 32 + m, col = ks * 16 + half * 8;
    if (g < MjT) *(uint4*)(bufA + c * 8) = *(const uint4*)(zg + basej + row * 128 + col);
    if (g < MiT) *(uint4*)(bufB + c * 8) = *(const uint4*)(zg + basei + row * 128 + col);
  }
  __syncthreads();
  int wr = wave >> 1, wc = wave & 1;          // 2x2 wave grid, 64x64 per wave
  int gA = wr * 2, gB = wc * 2;
  bool a0 = gA < MjT, a1 = (gA + 1) < MjT;
  bool b0 = gB < MiT, b1 = (gB + 1) < MiT;
  f32x16 acc[2][2] = {};
  if ((a0 || a1) && (b0 || b1)) {
    for (int ks = 0; ks < 8; ++ks) {
      bf16x8 aF[2], bF[2];
      if (a0) aF[0] = *(const bf16x8*)(bufA + ((gA    ) * 8 + ks) * 512 + lane * 8);
      if (a1) aF[1] = *(const bf16x8*)(bufA + ((gA + 1) * 8 + ks) * 512 + lane * 8);
      if (b0) bF[0] = *(const bf16x8*)(bufB + ((gB    ) * 8 + ks) * 512 + lane * 8);
      if (b1) bF[1] = *(const bf16x8*)(bufB + ((gB + 1) * 8 + ks) * 512 + lane * 8);
      if (a0 && b0) acc[0][0] = __builtin_amdgcn_mfma_f32_32x32x16_bf16(aF[0], bF[0], acc[0][0], 0, 0, 0);
      if (a0 && b1) acc[0][1] = __builtin_amdgcn_mfma_f32_32x32x16_bf16(aF[0], bF[1], acc[0][1], 0, 0, 0);
      if (a1 && b0) acc[1][0] = __builtin_amdgcn_mfma_f32_32x32x16_bf16(aF[1], bF[0], acc[1][0], 0, 0, 0);
      if (a1 && b1) acc[1][1] = __builtin_amdgcn_mfma_f32_32x32x16_bf16(aF[1], bF[1], acc[1][1], 0, 0, 0);
    }
  }
  float s1 = 0.f, s2 = 0.f;
#pragma unroll
  for (int ii = 0; ii < 2; ++ii)
#pragma unroll
    for (int jj = 0; jj < 2; ++jj) {
      bool act = (ii ? a1 : a0) && (jj ? b1 : b0);
      if (act)
#pragma unroll
        for (int r = 0; r < 16; ++r) {
          float a = acc[ii][jj][r];
          s1 += a; s2 += fabsf(a);
        }
    }
  for (int off = 1; off < 64; off <<= 1) {
    s1 += __shfl_xor(s1, off, 64);
    s2 += __shfl_xor(s2, off, 64);
  }
  if (lane == 0) { red[wave * 2] = s1; red[wave * 2 + 1] = s2; }
  __syncthreads();
  if (tid == 0) {
    float S1 = red[0] + red[2] + red[4] + red[6];
    float S2 = red[1] + red[3] + red[5] + red[7];
    const float rs = 0.08838834764831845f;
    float T = rs * (0.65f * S1 + 0.35f * S2);
    scores[((j * 48 + i) << 2) + hh] = T / ((float)si * 128.0f);
    scores[((i * 48 + j) << 2) + hh] = T / ((float)sj * 128.0f);
  }
}

__global__ __launch_bounds__(256) void final_kernel(
    const float* __restrict__ scores, const float* __restrict__ w2, float* __restrict__ out)
{
  int idx = blockIdx.x * 256 + threadIdx.x;
  if (idx >= 2304) return;
  float t = 0.f;
  for (int h = 0; h < 4; ++h) t += scores[idx * 4 + h] * w2[h];
  out[idx] = t;
}

// ---------------------------------------------------------------------------
extern "C" void kernel_launch(void* const* d_in, const int* in_sizes, int n_in,
                              void* d_out, int out_size, void* d_ws, size_t ws_size,
                              hipStream_t stream)
{
  const float* x     = (const float*)d_in[0];
  const int*   xsize = (const int*)d_in[1];
  const float* Wproj = (const float*)d_in[2];
  const float* Wq    = (const float*)d_in[3];
  const float* Wk    = (const float*)d_in[4];
  const float* Wv    = (const float*)d_in[5];
  const float* Wh    = (const float*)d_in[6];
  const float* Wfc   = (const float*)d_in[7];
  const float* Wc    = (const float*)d_in[8];
  const float* w2    = (const float*)d_in[9];
  float* out = (float*)d_out;

  char* ws = (char*)d_ws;
  size_t off = 0;
  auto alloc = [&](size_t bytes) -> char* {
    char* p = ws + off;
    off += (bytes + 255) & ~(size_t)255;
    return p;
  };
  u16*   wT    = (u16*)  alloc(638976 * 2);
  float* stats = (float*)alloc(384 * 4);         // 4 stages x 48 sets x {S1,S2}
  u16*   xb    = (u16*)  alloc(6144 * 128 * 2);
  float* valid = (float*)alloc(6144 * 4);
  float* hf    = (float*)alloc(6144 * 128 * 4);
  u16*   hb    = (u16*)  alloc(6144 * 128 * 2);
  float* uf    = (float*)alloc(6144 * 128 * 4);
  u16*   qb    = (u16*)  alloc((size_t)3145728 * 2);
  u16*   kb    = (u16*)  alloc((size_t)3145728 * 2);
  u16*   vTb   = (u16*)  alloc((size_t)3145728 * 2);
  u16*   ob    = (u16*)  alloc((size_t)6144 * 512 * 2);
  float* sc    = (float*)alloc(9216 * 4);

  prep_weights<<<2498, 256, 0, stream>>>(Wproj, Wq, Wk, Wv, Wh, Wfc, Wc, wT, stats);
  prep_x<<<6144, 128, 0, stream>>>(x, xb, valid);
  gemm_bt<<<dim3(96, 2), 256, 0, stream>>>(xb, wT, hf, hb, nullptr, nullptr,
                                           nullptr, valid, nullptr, 128, 128, 1);

  for (int l = 0; l < 2; ++l) {
    const u16* QKVT = wT + 16384 + l * 196608;
    const u16* WhT  = wT + 409600 + l * 65536;
    const u16* WfcT = wT + 540672 + l * 16384;
    float* st0 = stats + (l * 2 + 0) * 96;
    float* st1 = stats + (l * 2 + 1) * 96;
    gemm_bt<<<dim3(96, 24), 256, 0, stream>>>(hb, QKVT, nullptr, qb, kb, vTb,
                                              nullptr, nullptr, nullptr, 1536, 128, 6);
    attn_kernel<<<192, 256, 0, stream>>>(qb, kb, vTb, ob, xsize);
    gemm_bt<<<dim3(96, 2), 256, 0, stream>>>(ob, WhT, uf, nullptr, nullptr, nullptr,
                                             hf, valid, st0, 128, 512, 4);
    normalize<<<192, 256, 0, stream>>>(uf, hf, hb, valid, st0, xsize);
    gemm_bt<<<dim3(96, 2), 256, 0, stream>>>(hb, WfcT, uf, nullptr, nullptr, nullptr,
                                             hf, valid, st1, 128, 128, 5);
    normalize<<<192, 256, 0, stream>>>(uf, hf, hb, valid, st1, xsize);
  }

  const u16* WcT = wT + 573440;
  gemm_bt<<<dim3(96, 8), 256, 0, stream>>>(hb, WcT, nullptr, qb, qb, qb,
                                           nullptr, nullptr, nullptr, 512, 128, 6);
  cross_kernel<<<dim3(48, 48, 4), 256, 0, stream>>>(qb, sc, xsize);
  final_kernel<<<9, 256, 0, stream>>>(sc, w2, out);
}